// Round 1
// 6996.264 us; speedup vs baseline: 2.2818x; 2.2818x over previous
//
#include <hip/hip_runtime.h>
#include <math.h>

#define L_SEQ   2048
#define NEMBD   1024
#define DINNER  2048
#define DSTATE  16
#define DTRANK  64
#define DCONV   4
#define VOCAB   50257
#define NLAYERS 4

__device__ __forceinline__ float silu_f(float x) { return x / (1.f + __expf(-x)); }
__device__ __forceinline__ float softplus_f(float x) { return x > 20.f ? x : log1pf(__expf(x)); }

// ---------------- embedding gather: x[l,e] = emb_W[tok[l], e] ----------------
__global__ void embed_k(const int* __restrict__ tok, const float* __restrict__ W,
                        float* __restrict__ x) {
    int idx = blockIdx.x * 256 + threadIdx.x;           // over L_SEQ*NEMBD
    int l = idx >> 10, e = idx & 1023;
    x[idx] = W[(size_t)tok[l] * NEMBD + e];
}

// ---------------- rmsnorm over last dim (N=1024), one block per row ----------
__global__ void rmsnorm_k(const float* __restrict__ x, const float* __restrict__ w,
                          const float* __restrict__ b, float* __restrict__ o) {
    int l = blockIdx.x;
    const float* xr = x + (size_t)l * NEMBD;
    float ss = 0.f;
    for (int i = threadIdx.x; i < NEMBD; i += 256) { float v = xr[i]; ss += v * v; }
    __shared__ float red[4];
    for (int off = 32; off > 0; off >>= 1) ss += __shfl_down(ss, off, 64);
    if ((threadIdx.x & 63) == 0) red[threadIdx.x >> 6] = ss;
    __syncthreads();
    if (threadIdx.x == 0) {
        float t = red[0] + red[1] + red[2] + red[3];
        red[0] = rsqrtf(t / (float)NEMBD + 1e-6f);
    }
    __syncthreads();
    float inv = red[0];
    for (int i = threadIdx.x; i < NEMBD; i += 256)
        o[(size_t)l * NEMBD + i] = xr[i] * inv * w[i] + b[i];
}

// ---------------- depthwise causal conv (width 4) + bias + silu --------------
__global__ void conv_silu_k(const float* __restrict__ xr, const float* __restrict__ cw,
                            const float* __restrict__ cb, float* __restrict__ xc) {
    int idx = blockIdx.x * 256 + threadIdx.x;           // over L_SEQ*DINNER
    int d = idx & (DINNER - 1); int l = idx >> 11;
    const float* w = cw + (size_t)d * DCONV;
    float acc = cb[d];
#pragma unroll
    for (int j = 0; j < DCONV; j++) {
        int t = l - (DCONV - 1) + j;
        if (t >= 0) acc = fmaf(xr[(size_t)t * (2 * DINNER) + d], w[j], acc);
    }
    xc[idx] = silu_f(acc);
}

// ---------------- zero fill ----------------
__global__ void zero_k(float* __restrict__ p, int n) {
    int i = blockIdx.x * 256 + threadIdx.x;
    if (i < n) p[i] = 0.f;
}

// ---------------- GEMM: C[M,N] = A[M,K] @ B[N,K]^T ---------------------------
// EPI: 0 = store; 1 = softplus(acc + bias[n]); 3 = atomicAdd (split-K partials)
// Requirements (all call sites satisfy): M % 128 == 0, K % (16*gridDim.y) == 0.
// Block order is y-fastest (bid % nyt = M-tile) so resident blocks share B panels.
#define BM 128
#define BN 128
#define BK 16
template <int EPI>
__global__ __launch_bounds__(256) void gemm_bt(
    const float* __restrict__ A, int lda,
    const float* __restrict__ B, int ldb,
    float* __restrict__ C, int ldc,
    const float* __restrict__ bias,
    int M, int N, int K, int nyt) {
    __shared__ __align__(16) float As[BK][BM + 4];
    __shared__ __align__(16) float Bs[BK][BN + 4];
    int tid = threadIdx.x;
    int bid = blockIdx.x;
    int bm = (bid % nyt) * BM;
    int bn = (bid / nyt) * BN;
    int Kc = K / (int)gridDim.y;
    int kb = blockIdx.y * Kc;
    int ke = kb + Kc;

    // staging: thread t loads rows (t>>2) and 64+(t>>2), k-cols (t&3)*4 .. +3
    int sr = tid >> 2;                 // 0..63
    int sc = (tid & 3) << 2;           // 0,4,8,12
    const float* Ap0 = A + (size_t)(bm + sr) * lda + sc;
    const float* Ap1 = Ap0 + (size_t)64 * lda;
    int br0 = bn + sr;      if (br0 > N - 1) br0 = N - 1;   // clamp (stores guarded)
    int br1 = bn + 64 + sr; if (br1 > N - 1) br1 = N - 1;
    const float* Bp0 = B + (size_t)br0 * ldb + sc;
    const float* Bp1 = B + (size_t)br1 * ldb + sc;

    float4 a0 = *(const float4*)(Ap0 + kb);
    float4 a1 = *(const float4*)(Ap1 + kb);
    float4 b0 = *(const float4*)(Bp0 + kb);
    float4 b1 = *(const float4*)(Bp1 + kb);

    int tx4 = (tid & 15) << 2;         // col group
    int ty4 = (tid >> 4) << 2;         // row group (0..60)
    float acc[8][8] = {};

    for (int k0 = kb; k0 < ke; k0 += BK) {
        // write staged regs to LDS (transposed: [k][m]); 2-way bank alias = free
        As[sc + 0][sr] = a0.x; As[sc + 1][sr] = a0.y;
        As[sc + 2][sr] = a0.z; As[sc + 3][sr] = a0.w;
        As[sc + 0][64 + sr] = a1.x; As[sc + 1][64 + sr] = a1.y;
        As[sc + 2][64 + sr] = a1.z; As[sc + 3][64 + sr] = a1.w;
        Bs[sc + 0][sr] = b0.x; Bs[sc + 1][sr] = b0.y;
        Bs[sc + 2][sr] = b0.z; Bs[sc + 3][sr] = b0.w;
        Bs[sc + 0][64 + sr] = b1.x; Bs[sc + 1][64 + sr] = b1.y;
        Bs[sc + 2][64 + sr] = b1.z; Bs[sc + 3][64 + sr] = b1.w;
        __syncthreads();
        // issue next tile's global loads; they stay in flight across compute
        if (k0 + BK < ke) {
            a0 = *(const float4*)(Ap0 + k0 + BK);
            a1 = *(const float4*)(Ap1 + k0 + BK);
            b0 = *(const float4*)(Bp0 + k0 + BK);
            b1 = *(const float4*)(Bp1 + k0 + BK);
        }
#pragma unroll
        for (int k = 0; k < BK; k++) {
            float4 av0 = *(const float4*)&As[k][ty4];        // broadcast: free
            float4 av1 = *(const float4*)&As[k][64 + ty4];
            float4 bv0 = *(const float4*)&Bs[k][tx4];        // contiguous: conflict-free
            float4 bv1 = *(const float4*)&Bs[k][64 + tx4];
            float av[8] = {av0.x, av0.y, av0.z, av0.w, av1.x, av1.y, av1.z, av1.w};
            float bv[8] = {bv0.x, bv0.y, bv0.z, bv0.w, bv1.x, bv1.y, bv1.z, bv1.w};
#pragma unroll
            for (int i = 0; i < 8; i++)
#pragma unroll
                for (int j = 0; j < 8; j++)
                    acc[i][j] = fmaf(av[i], bv[j], acc[i][j]);
        }
        __syncthreads();
    }

#pragma unroll
    for (int i = 0; i < 8; i++) {
        int gm = bm + (i < 4 ? ty4 + i : 64 + ty4 + i - 4);
#pragma unroll
        for (int j = 0; j < 8; j++) {
            int gn = bn + (j < 4 ? tx4 + j : 64 + tx4 + j - 4);
            if (gn >= N) continue;
            float v = acc[i][j];
            size_t off = (size_t)gm * ldc + gn;
            if (EPI == 0) C[off] = v;
            if (EPI == 1) C[off] = softplus_f(v + bias[gn]);
            if (EPI == 3) atomicAdd(&C[off], v);
        }
    }
}

// ---------------- selective scan: 16 lanes per channel (one per state) -------
// lane (d,n): s = exp(dlt*a_n)*s + dlt*u*B[l,n]; y[l,d] = (sum_n s*C[l,n] + u*Dd)*silu(res)
// 512 blocks x 64 threads; ping-pong register prefetch 8 steps deep.
__global__ __launch_bounds__(64) void scan_k(
    const float* __restrict__ xc, const float* __restrict__ delta,
    const float* __restrict__ xdbl, const float* __restrict__ Alog,
    const float* __restrict__ Dpv, const float* __restrict__ xr,
    float* __restrict__ y) {
    int gid = blockIdx.x * 64 + threadIdx.x;    // over DINNER*DSTATE
    int d = gid >> 4;
    int n = gid & 15;
    float a = -__expf(Alog[(size_t)d * DSTATE + n]);
    float Dd = Dpv[d];
    float s = 0.f;

    float dA[8], uA[8], BA[8], CA[8], rA[8];
    float dB[8], uB[8], BB[8], CB[8], rB[8];

#define LOADG(DL, UU, BV, CV, RR, lbase)                              \
    _Pragma("unroll")                                                 \
    for (int j = 0; j < 8; j++) {                                     \
        int ll = (lbase) + j; if (ll > L_SEQ - 1) ll = L_SEQ - 1;     \
        DL[j] = delta[(size_t)ll * DINNER + d];                       \
        UU[j] = xc[(size_t)ll * DINNER + d];                          \
        BV[j] = xdbl[(size_t)ll * 96 + DTRANK + n];                   \
        CV[j] = xdbl[(size_t)ll * 96 + DTRANK + DSTATE + n];          \
        RR[j] = xr[(size_t)ll * (2 * DINNER) + DINNER + d];           \
    }

#define STEP8(DL, UU, BV, CV, RR, lbase)                              \
    _Pragma("unroll")                                                 \
    for (int j = 0; j < 8; j++) {                                     \
        float e = __expf(DL[j] * a);                                  \
        s = fmaf(e, s, DL[j] * UU[j] * BV[j]);                        \
        float p = s * CV[j];                                          \
        p += __shfl_xor(p, 1, 64);                                    \
        p += __shfl_xor(p, 2, 64);                                    \
        p += __shfl_xor(p, 4, 64);                                    \
        p += __shfl_xor(p, 8, 64);                                    \
        if (n == 0)                                                   \
            y[(size_t)((lbase) + j) * DINNER + d] =                   \
                fmaf(UU[j], Dd, p) * silu_f(RR[j]);                   \
    }

    LOADG(dA, uA, BA, CA, rA, 0)
    for (int l0 = 0; l0 < L_SEQ; l0 += 16) {
        LOADG(dB, uB, BB, CB, rB, l0 + 8)
        STEP8(dA, uA, BA, CA, rA, l0)
        LOADG(dA, uA, BA, CA, rA, l0 + 16)
        STEP8(dB, uB, BB, CB, rB, l0 + 8)
    }
#undef LOADG
#undef STEP8
}

extern "C" void kernel_launch(void* const* d_in, const int* in_sizes, int n_in,
                              void* d_out, int out_size, void* d_ws, size_t ws_size,
                              hipStream_t stream) {
    (void)in_sizes; (void)n_in; (void)out_size; (void)ws_size;
    const int*   tokens    = (const int*)d_in[0];
    const float* emb_W     = (const float*)d_in[1];
    const float* in_proj_W = (const float*)d_in[2];
    const float* conv_W    = (const float*)d_in[3];
    const float* conv_b    = (const float*)d_in[4];
    const float* xproj_W   = (const float*)d_in[5];
    const float* dt_W      = (const float*)d_in[6];
    const float* dt_b      = (const float*)d_in[7];
    const float* A_log     = (const float*)d_in[8];
    const float* Dp        = (const float*)d_in[9];
    const float* out_W     = (const float*)d_in[10];
    const float* rms_w     = (const float*)d_in[11];
    const float* rms_b     = (const float*)d_in[12];
    const float* normf_w   = (const float*)d_in[13];
    const float* normf_b   = (const float*)d_in[14];
    float* out = (float*)d_out;

    float* ws   = (float*)d_ws;
    float* x    = ws;                                  // [L, 1024]
    float* h    = x    + (size_t)L_SEQ * NEMBD;        // [L, 1024]
    float* xr   = h    + (size_t)L_SEQ * NEMBD;        // [L, 4096]
    float* xc   = xr   + (size_t)L_SEQ * 2 * DINNER;   // [L, 2048]
    float* xdbl = xc   + (size_t)L_SEQ * DINNER;       // [L, 96]
    float* dlt  = xdbl + (size_t)L_SEQ * 96;           // [L, 2048]
    float* y    = dlt  + (size_t)L_SEQ * DINNER;       // [L, 2048]

    dim3 blk(256);

    embed_k<<<(L_SEQ * NEMBD) / 256, blk, 0, stream>>>(tokens, emb_W, x);

    for (int i = 0; i < NLAYERS; i++) {
        const float* ipW = in_proj_W + (size_t)i * 2 * DINNER * NEMBD;
        const float* cW  = conv_W   + (size_t)i * DINNER * DCONV;
        const float* cB  = conv_b   + (size_t)i * DINNER;
        const float* xpW = xproj_W  + (size_t)i * 96 * DINNER;
        const float* dW  = dt_W     + (size_t)i * DINNER * DTRANK;
        const float* dB  = dt_b     + (size_t)i * DINNER;
        const float* Al  = A_log    + (size_t)i * DINNER * DSTATE;
        const float* Dl  = Dp       + (size_t)i * DINNER;
        const float* oW  = out_W    + (size_t)i * NEMBD * DINNER;

        // h = rmsnorm(x)
        rmsnorm_k<<<L_SEQ, blk, 0, stream>>>(x, rms_w + (size_t)i * NEMBD,
                                             rms_b + (size_t)i * NEMBD, h);
        // xr = h @ in_proj^T  [L, 4096]   (32 N-tiles x 16 M-tiles)
        gemm_bt<0><<<dim3(32 * 16, 1), blk, 0, stream>>>(
            h, NEMBD, ipW, NEMBD, xr, 2 * DINNER, nullptr,
            L_SEQ, 2 * DINNER, NEMBD, 16);
        // xc = silu(causal_conv(xr[:, :DINNER]) + conv_b)
        conv_silu_k<<<(L_SEQ * DINNER) / 256, blk, 0, stream>>>(xr, cW, cB, xc);
        // xdbl = xc @ xproj^T  [L, 96]  — split-K x8 into zeroed buffer
        zero_k<<<(L_SEQ * 96) / 256, blk, 0, stream>>>(xdbl, L_SEQ * 96);
        gemm_bt<3><<<dim3(1 * 16, 8), blk, 0, stream>>>(
            xc, DINNER, xpW, DINNER, xdbl, 96, nullptr,
            L_SEQ, 96, DINNER, 16);
        // delta = softplus(xdbl[:, :64] @ dt_W^T + dt_b)  [L, 2048]
        gemm_bt<1><<<dim3(16 * 16, 1), blk, 0, stream>>>(
            xdbl, 96, dW, DTRANK, dlt, DINNER, dB,
            L_SEQ, DINNER, DTRANK, 16);
        // selective scan (+ fused y *= silu(res)) -> y
        scan_k<<<(DINNER * DSTATE) / 64, dim3(64), 0, stream>>>(
            xc, dlt, xdbl, Al, Dl, xr, y);
        // x += y @ out_W^T  — split-K x2 with atomic accumulate into x
        gemm_bt<3><<<dim3(8 * 16, 2), blk, 0, stream>>>(
            y, DINNER, oW, DINNER, x, NEMBD, nullptr,
            L_SEQ, NEMBD, DINNER, 16);
    }

    // final norm + tied LM head
    rmsnorm_k<<<L_SEQ, blk, 0, stream>>>(x, normf_w, normf_b, h);
    gemm_bt<0><<<dim3(393 * 16, 1), blk, 0, stream>>>(
        h, NEMBD, emb_W, NEMBD, out, VOCAB, nullptr,
        L_SEQ, VOCAB, NEMBD, 16);
}

// Round 3
// 5844.867 us; speedup vs baseline: 2.7313x; 1.1970x over previous
//
#include <hip/hip_runtime.h>
#include <math.h>

#define L_SEQ   2048
#define NEMBD   1024
#define DINNER  2048
#define DSTATE  16
#define DTRANK  64
#define DCONV   4
#define VOCAB   50257
#define NLAYERS 4
#define VOCAB_PAD 50304   /* 393*128 */

typedef _Float16 f16x8 __attribute__((ext_vector_type(8)));
typedef float f32x4 __attribute__((ext_vector_type(4)));

__device__ __forceinline__ float silu_f(float x) { return x / (1.f + __expf(-x)); }
__device__ __forceinline__ float softplus_f(float x) { return x > 20.f ? x : log1pf(__expf(x)); }

// ---------------- embedding gather: x[l,e] = emb_W[tok[l], e] ----------------
__global__ void embed_k(const int* __restrict__ tok, const float* __restrict__ W,
                        float* __restrict__ x) {
    int idx = blockIdx.x * 256 + threadIdx.x;           // over L_SEQ*NEMBD
    int l = idx >> 10, e = idx & 1023;
    x[idx] = W[(size_t)tok[l] * NEMBD + e];
}

// ---------------- rmsnorm over last dim (N=1024), one block per row ----------
__global__ void rmsnorm_k(const float* __restrict__ x, const float* __restrict__ w,
                          const float* __restrict__ b, float* __restrict__ o) {
    int l = blockIdx.x;
    const float* xr = x + (size_t)l * NEMBD;
    float ss = 0.f;
    for (int i = threadIdx.x; i < NEMBD; i += 256) { float v = xr[i]; ss += v * v; }
    __shared__ float red[4];
    for (int off = 32; off > 0; off >>= 1) ss += __shfl_down(ss, off, 64);
    if ((threadIdx.x & 63) == 0) red[threadIdx.x >> 6] = ss;
    __syncthreads();
    if (threadIdx.x == 0) {
        float t = red[0] + red[1] + red[2] + red[3];
        red[0] = rsqrtf(t / (float)NEMBD + 1e-6f);
    }
    __syncthreads();
    float inv = red[0];
    for (int i = threadIdx.x; i < NEMBD; i += 256)
        o[(size_t)l * NEMBD + i] = xr[i] * inv * w[i] + b[i];
}

// ---------------- depthwise causal conv (width 4) + bias + silu --------------
__global__ void conv_silu_k(const float* __restrict__ xr, const float* __restrict__ cw,
                            const float* __restrict__ cb, float* __restrict__ xc) {
    int idx = blockIdx.x * 256 + threadIdx.x;           // over L_SEQ*DINNER
    int d = idx & (DINNER - 1); int l = idx >> 11;
    const float* w = cw + (size_t)d * DCONV;
    float acc = cb[d];
#pragma unroll
    for (int j = 0; j < DCONV; j++) {
        int t = l - (DCONV - 1) + j;
        if (t >= 0) acc = fmaf(xr[(size_t)t * (2 * DINNER) + d], w[j], acc);
    }
    xc[idx] = silu_f(acc);
}

// ---------------- zero fill ----------------
__global__ void zero_k(float* __restrict__ p, int n) {
    int i = blockIdx.x * 256 + threadIdx.x;
    if (i < n) p[i] = 0.f;
}

// ---------------- f32 -> f16 conversion, 8 elems/thread ----------------------
__global__ void cvt_f16_k(const float* __restrict__ s, unsigned short* __restrict__ d,
                          int n8) {
    int i = blockIdx.x * 256 + threadIdx.x;
    if (i >= n8) return;
    float4 v0 = ((const float4*)s)[(size_t)i * 2];
    float4 v1 = ((const float4*)s)[(size_t)i * 2 + 1];
    union { _Float16 h[8]; uint4 u; } r;
    r.h[0] = (_Float16)v0.x; r.h[1] = (_Float16)v0.y;
    r.h[2] = (_Float16)v0.z; r.h[3] = (_Float16)v0.w;
    r.h[4] = (_Float16)v1.x; r.h[5] = (_Float16)v1.y;
    r.h[6] = (_Float16)v1.z; r.h[7] = (_Float16)v1.w;
    ((uint4*)d)[i] = r.u;
}

// ---------------- fp16 MFMA GEMM: C[M,N] = A[M,K] @ B[N,K]^T -----------------
// A,B f16 row-major (lda/ldb elems, %8==0); C f32. M%128==0, K%64==0.
// B must be readable up to row (gridDim.x/mtiles)*128-1 (pad rows zeroed).
// Block order M-fastest for B-panel L2 reuse.
// Tile 128x128, BK=64, 4 waves in 2x2, each wave 64x64 = 4x4 frags of 16x16x32.
// LDS XOR-swizzle: 16-byte chunk index ^= (row&7)  (T2; kills the stride-128B
// same-bank pattern on both ds_write and ds_read sides).
__global__ __launch_bounds__(256) void gemm_f16(
    const unsigned short* __restrict__ A, int lda,
    const unsigned short* __restrict__ B, int ldb,
    float* __restrict__ C, int ldc,
    int N, int K, int mtiles) {
    __shared__ unsigned short As[128 * 64];
    __shared__ unsigned short Bs[128 * 64];
    int bid = blockIdx.x;
    int bm = (bid % mtiles) << 7;
    int bn = (bid / mtiles) << 7;
    int tid = threadIdx.x;
    int lane = tid & 63;
    int wc = (tid >> 6) & 1;
    int wr = tid >> 7;

    // staging: thread covers one 16B chunk of 4 rows; row=tid>>3 (+32/i), chunk=tid&7
    int srow = tid >> 3;                                   // 0..31, +32 per i
    int kcol = (tid & 7) << 3;                             // element col
    int swoff = (((tid & 7) ^ ((tid >> 3) & 7)) << 3);     // swizzled col
    const unsigned short* Ab = A + (size_t)(bm + srow) * lda + kcol;
    const unsigned short* Bb = B + (size_t)(bn + srow) * ldb + kcol;
    unsigned short* AsW = As + srow * 64 + swoff;
    unsigned short* BsW = Bs + srow * 64 + swoff;

    uint4 ra[4], rb[4];
#pragma unroll
    for (int i = 0; i < 4; i++) {
        ra[i] = *(const uint4*)(Ab + (size_t)(i * 32) * lda);
        rb[i] = *(const uint4*)(Bb + (size_t)(i * 32) * ldb);
    }

    int q = lane >> 4;          // k-quarter
    int fr = lane & 15;         // fragment row (A) / fragment col-row (B)
    f32x4 acc[4][4] = {};

    int nk = K >> 6;
    for (int kt = 0; kt < nk; kt++) {
        __syncthreads();                  // previous tile's compute done
#pragma unroll
        for (int i = 0; i < 4; i++) {
            *(uint4*)(AsW + i * (32 * 64)) = ra[i];
            *(uint4*)(BsW + i * (32 * 64)) = rb[i];
        }
        __syncthreads();                  // tile visible
        if (kt + 1 < nk) {                // prefetch next tile; in flight across MFMA
            int k0 = (kt + 1) << 6;
#pragma unroll
            for (int i = 0; i < 4; i++) {
                ra[i] = *(const uint4*)(Ab + (size_t)(i * 32) * lda + k0);
                rb[i] = *(const uint4*)(Bb + (size_t)(i * 32) * ldb + k0);
            }
        }
#pragma unroll
        for (int kk = 0; kk < 2; kk++) {
            f16x8 af[4], bf[4];
#pragma unroll
            for (int mf = 0; mf < 4; mf++) {
                int row = wr * 64 + mf * 16 + fr;
                int ch = (kk * 4 + q) ^ (row & 7);
                af[mf] = *(const f16x8*)(As + row * 64 + ch * 8);
            }
#pragma unroll
            for (int nf = 0; nf < 4; nf++) {
                int row = wc * 64 + nf * 16 + fr;
                int ch = (kk * 4 + q) ^ (row & 7);
                bf[nf] = *(const f16x8*)(Bs + row * 64 + ch * 8);
            }
#pragma unroll
            for (int mf = 0; mf < 4; mf++)
#pragma unroll
                for (int nf = 0; nf < 4; nf++)
                    acc[mf][nf] = __builtin_amdgcn_mfma_f32_16x16x32_f16(
                        af[mf], bf[nf], acc[mf][nf], 0, 0, 0);
        }
    }

    // C/D layout (verified m89/m91): col = lane&15, row = (lane>>4)*4 + reg
    int crow0 = bm + wr * 64 + (lane >> 4) * 4;
    int ccol0 = bn + wc * 64 + (lane & 15);
#pragma unroll
    for (int mf = 0; mf < 4; mf++)
#pragma unroll
        for (int nf = 0; nf < 4; nf++) {
            int gcol = ccol0 + nf * 16;
            if (gcol >= N) continue;
            float* cp = C + (size_t)(crow0 + mf * 16) * ldc + gcol;
#pragma unroll
            for (int r = 0; r < 4; r++)
                cp[(size_t)r * ldc] = acc[mf][nf][r];
        }
}

// ---------------- fp32 GEMM: C[M,N] = A[M,K] @ B[N,K]^T ----------------------
// EPI: 0 = store; 1 = softplus(acc + bias[n]); 3 = atomicAdd (split-K partials)
#define BM 128
#define BN 128
#define BK 16
template <int EPI>
__global__ __launch_bounds__(256) void gemm_bt(
    const float* __restrict__ A, int lda,
    const float* __restrict__ B, int ldb,
    float* __restrict__ C, int ldc,
    const float* __restrict__ bias,
    int M, int N, int K, int nyt) {
    __shared__ __align__(16) float As[BK][BM + 4];
    __shared__ __align__(16) float Bs[BK][BN + 4];
    int tid = threadIdx.x;
    int bid = blockIdx.x;
    int bm = (bid % nyt) * BM;
    int bn = (bid / nyt) * BN;
    int Kc = K / (int)gridDim.y;
    int kb = blockIdx.y * Kc;
    int ke = kb + Kc;

    int sr = tid >> 2;                 // 0..63
    int sc = (tid & 3) << 2;           // 0,4,8,12
    const float* Ap0 = A + (size_t)(bm + sr) * lda + sc;
    const float* Ap1 = Ap0 + (size_t)64 * lda;
    int br0 = bn + sr;      if (br0 > N - 1) br0 = N - 1;
    int br1 = bn + 64 + sr; if (br1 > N - 1) br1 = N - 1;
    const float* Bp0 = B + (size_t)br0 * ldb + sc;
    const float* Bp1 = B + (size_t)br1 * ldb + sc;

    float4 a0 = *(const float4*)(Ap0 + kb);
    float4 a1 = *(const float4*)(Ap1 + kb);
    float4 b0 = *(const float4*)(Bp0 + kb);
    float4 b1 = *(const float4*)(Bp1 + kb);

    int tx4 = (tid & 15) << 2;
    int ty4 = (tid >> 4) << 2;
    float acc[8][8] = {};

    for (int k0 = kb; k0 < ke; k0 += BK) {
        As[sc + 0][sr] = a0.x; As[sc + 1][sr] = a0.y;
        As[sc + 2][sr] = a0.z; As[sc + 3][sr] = a0.w;
        As[sc + 0][64 + sr] = a1.x; As[sc + 1][64 + sr] = a1.y;
        As[sc + 2][64 + sr] = a1.z; As[sc + 3][64 + sr] = a1.w;
        Bs[sc + 0][sr] = b0.x; Bs[sc + 1][sr] = b0.y;
        Bs[sc + 2][sr] = b0.z; Bs[sc + 3][sr] = b0.w;
        Bs[sc + 0][64 + sr] = b1.x; Bs[sc + 1][64 + sr] = b1.y;
        Bs[sc + 2][64 + sr] = b1.z; Bs[sc + 3][64 + sr] = b1.w;
        __syncthreads();
        if (k0 + BK < ke) {
            a0 = *(const float4*)(Ap0 + k0 + BK);
            a1 = *(const float4*)(Ap1 + k0 + BK);
            b0 = *(const float4*)(Bp0 + k0 + BK);
            b1 = *(const float4*)(Bp1 + k0 + BK);
        }
#pragma unroll
        for (int k = 0; k < BK; k++) {
            float4 av0 = *(const float4*)&As[k][ty4];
            float4 av1 = *(const float4*)&As[k][64 + ty4];
            float4 bv0 = *(const float4*)&Bs[k][tx4];
            float4 bv1 = *(const float4*)&Bs[k][64 + tx4];
            float av[8] = {av0.x, av0.y, av0.z, av0.w, av1.x, av1.y, av1.z, av1.w};
            float bv[8] = {bv0.x, bv0.y, bv0.z, bv0.w, bv1.x, bv1.y, bv1.z, bv1.w};
#pragma unroll
            for (int i = 0; i < 8; i++)
#pragma unroll
                for (int j = 0; j < 8; j++)
                    acc[i][j] = fmaf(av[i], bv[j], acc[i][j]);
        }
        __syncthreads();
    }

#pragma unroll
    for (int i = 0; i < 8; i++) {
        int gm = bm + (i < 4 ? ty4 + i : 64 + ty4 + i - 4);
#pragma unroll
        for (int j = 0; j < 8; j++) {
            int gn = bn + (j < 4 ? tx4 + j : 64 + tx4 + j - 4);
            if (gn >= N) continue;
            float v = acc[i][j];
            size_t off = (size_t)gm * ldc + gn;
            if (EPI == 0) C[off] = v;
            if (EPI == 1) C[off] = softplus_f(v + bias[gn]);
            if (EPI == 3) atomicAdd(&C[off], v);
        }
    }
}

// ---------------- selective scan: 16 lanes per channel (one per state) -------
__global__ __launch_bounds__(64) void scan_k(
    const float* __restrict__ xc, const float* __restrict__ delta,
    const float* __restrict__ xdbl, const float* __restrict__ Alog,
    const float* __restrict__ Dpv, const float* __restrict__ xr,
    float* __restrict__ y) {
    int gid = blockIdx.x * 64 + threadIdx.x;    // over DINNER*DSTATE
    int d = gid >> 4;
    int n = gid & 15;
    float a = -__expf(Alog[(size_t)d * DSTATE + n]);
    float Dd = Dpv[d];
    float s = 0.f;

    float dA[8], uA[8], BA[8], CA[8], rA[8];
    float dB[8], uB[8], BB[8], CB[8], rB[8];

#define LOADG(DL, UU, BV, CV, RR, lbase)                              \
    _Pragma("unroll")                                                 \
    for (int j = 0; j < 8; j++) {                                     \
        int ll = (lbase) + j; if (ll > L_SEQ - 1) ll = L_SEQ - 1;     \
        DL[j] = delta[(size_t)ll * DINNER + d];                       \
        UU[j] = xc[(size_t)ll * DINNER + d];                          \
        BV[j] = xdbl[(size_t)ll * 96 + DTRANK + n];                   \
        CV[j] = xdbl[(size_t)ll * 96 + DTRANK + DSTATE + n];          \
        RR[j] = xr[(size_t)ll * (2 * DINNER) + DINNER + d];           \
    }

#define STEP8(DL, UU, BV, CV, RR, lbase)                              \
    _Pragma("unroll")                                                 \
    for (int j = 0; j < 8; j++) {                                     \
        float e = __expf(DL[j] * a);                                  \
        s = fmaf(e, s, DL[j] * UU[j] * BV[j]);                        \
        float p = s * CV[j];                                          \
        p += __shfl_xor(p, 1, 64);                                    \
        p += __shfl_xor(p, 2, 64);                                    \
        p += __shfl_xor(p, 4, 64);                                    \
        p += __shfl_xor(p, 8, 64);                                    \
        if (n == 0)                                                   \
            y[(size_t)((lbase) + j) * DINNER + d] =                   \
                fmaf(UU[j], Dd, p) * silu_f(RR[j]);                   \
    }

    LOADG(dA, uA, BA, CA, rA, 0)
    for (int l0 = 0; l0 < L_SEQ; l0 += 16) {
        LOADG(dB, uB, BB, CB, rB, l0 + 8)
        STEP8(dA, uA, BA, CA, rA, l0)
        LOADG(dA, uA, BA, CA, rA, l0 + 16)
        STEP8(dB, uB, BB, CB, rB, l0 + 8)
    }
#undef LOADG
#undef STEP8
}

extern "C" void kernel_launch(void* const* d_in, const int* in_sizes, int n_in,
                              void* d_out, int out_size, void* d_ws, size_t ws_size,
                              hipStream_t stream) {
    (void)in_sizes; (void)n_in; (void)out_size;
    const int*   tokens    = (const int*)d_in[0];
    const float* emb_W     = (const float*)d_in[1];
    const float* in_proj_W = (const float*)d_in[2];
    const float* conv_W    = (const float*)d_in[3];
    const float* conv_b    = (const float*)d_in[4];
    const float* xproj_W   = (const float*)d_in[5];
    const float* dt_W      = (const float*)d_in[6];
    const float* dt_b      = (const float*)d_in[7];
    const float* A_log     = (const float*)d_in[8];
    const float* Dp        = (const float*)d_in[9];
    const float* out_W     = (const float*)d_in[10];
    const float* rms_w     = (const float*)d_in[11];
    const float* rms_b     = (const float*)d_in[12];
    const float* normf_w   = (const float*)d_in[13];
    const float* normf_b   = (const float*)d_in[14];
    float* out = (float*)d_out;

    float* ws   = (float*)d_ws;
    float* x    = ws;                                  // [L, 1024]
    float* h    = x    + (size_t)L_SEQ * NEMBD;        // [L, 1024]
    float* xr   = h    + (size_t)L_SEQ * NEMBD;        // [L, 4096]
    float* xc   = xr   + (size_t)L_SEQ * 2 * DINNER;   // [L, 2048]
    float* xdbl = xc   + (size_t)L_SEQ * DINNER;       // [L, 96]
    float* dlt  = xdbl + (size_t)L_SEQ * 96;           // [L, 2048]
    float* y    = dlt  + (size_t)L_SEQ * DINNER;       // [L, 2048]

    size_t f32_elems = (size_t)L_SEQ * (2 * NEMBD + 2 * DINNER + DINNER + 96 + DINNER + DINNER);
    unsigned short* embH = (unsigned short*)(ws + f32_elems);   // [VOCAB_PAD,1024] f16
    unsigned short* hH   = embH + (size_t)VOCAB_PAD * NEMBD;    // [L,1024] f16
    size_t need = f32_elems * 4 + (size_t)VOCAB_PAD * NEMBD * 2 + (size_t)L_SEQ * NEMBD * 2;
    bool use_f16_head = (ws_size >= need);

    dim3 blk(256);

    embed_k<<<(L_SEQ * NEMBD) / 256, blk, 0, stream>>>(tokens, emb_W, x);

    for (int i = 0; i < NLAYERS; i++) {
        const float* ipW = in_proj_W + (size_t)i * 2 * DINNER * NEMBD;
        const float* cW  = conv_W   + (size_t)i * DINNER * DCONV;
        const float* cB  = conv_b   + (size_t)i * DINNER;
        const float* xpW = xproj_W  + (size_t)i * 96 * DINNER;
        const float* dW  = dt_W     + (size_t)i * DINNER * DTRANK;
        const float* dB  = dt_b     + (size_t)i * DINNER;
        const float* Al  = A_log    + (size_t)i * DINNER * DSTATE;
        const float* Dl  = Dp       + (size_t)i * DINNER;
        const float* oW  = out_W    + (size_t)i * NEMBD * DINNER;

        // h = rmsnorm(x)
        rmsnorm_k<<<L_SEQ, blk, 0, stream>>>(x, rms_w + (size_t)i * NEMBD,
                                             rms_b + (size_t)i * NEMBD, h);
        // xr = h @ in_proj^T  [L, 4096]
        gemm_bt<0><<<dim3(32 * 16, 1), blk, 0, stream>>>(
            h, NEMBD, ipW, NEMBD, xr, 2 * DINNER, nullptr,
            L_SEQ, 2 * DINNER, NEMBD, 16);
        // xc = silu(causal_conv(xr[:, :DINNER]) + conv_b)
        conv_silu_k<<<(L_SEQ * DINNER) / 256, blk, 0, stream>>>(xr, cW, cB, xc);
        // xdbl = xc @ xproj^T  [L, 96]  — split-K x8 into zeroed buffer
        zero_k<<<(L_SEQ * 96) / 256, blk, 0, stream>>>(xdbl, L_SEQ * 96);
        gemm_bt<3><<<dim3(1 * 16, 8), blk, 0, stream>>>(
            xc, DINNER, xpW, DINNER, xdbl, 96, nullptr,
            L_SEQ, 96, DINNER, 16);
        // delta = softplus(xdbl[:, :64] @ dt_W^T + dt_b)  [L, 2048]
        gemm_bt<1><<<dim3(16 * 16, 1), blk, 0, stream>>>(
            xdbl, 96, dW, DTRANK, dlt, DINNER, dB,
            L_SEQ, DINNER, DTRANK, 16);
        // selective scan (+ fused y *= silu(res)) -> y
        scan_k<<<(DINNER * DSTATE) / 64, dim3(64), 0, stream>>>(
            xc, dlt, xdbl, Al, Dl, xr, y);
        // x += y @ out_W^T  — split-K x2 with atomic accumulate into x
        gemm_bt<3><<<dim3(8 * 16, 2), blk, 0, stream>>>(
            y, DINNER, oW, DINNER, x, NEMBD, nullptr,
            L_SEQ, NEMBD, DINNER, 16);
    }

    // final norm + tied LM head
    rmsnorm_k<<<L_SEQ, blk, 0, stream>>>(x, normf_w, normf_b, h);
    if (use_f16_head) {
        // zero the pad rows of embH (50257..50303) so no uninitialized reads
        zero_k<<<(((VOCAB_PAD - VOCAB) * NEMBD / 2) + 255) / 256, blk, 0, stream>>>(
            (float*)(embH + (size_t)VOCAB * NEMBD), (VOCAB_PAD - VOCAB) * NEMBD / 2);
        int n8e = VOCAB * NEMBD / 8;
        cvt_f16_k<<<(n8e + 255) / 256, blk, 0, stream>>>(emb_W, embH, n8e);
        int n8h = L_SEQ * NEMBD / 8;
        cvt_f16_k<<<(n8h + 255) / 256, blk, 0, stream>>>(h, hH, n8h);
        gemm_f16<<<dim3((VOCAB_PAD / 128) * 16), blk, 0, stream>>>(
            hH, NEMBD, embH, NEMBD, out, VOCAB, VOCAB, NEMBD, 16);
    } else {
        gemm_bt<0><<<dim3(393 * 16, 1), blk, 0, stream>>>(
            h, NEMBD, emb_W, NEMBD, out, VOCAB, nullptr,
            L_SEQ, VOCAB, NEMBD, 16);
    }
}